// Round 2
// baseline (568.263 us; speedup 1.0000x reference)
//
#include <hip/hip_runtime.h>

// Problem constants (fixed by the reference).
#define NT   131072      // total nodes
#define ET   2097152     // edges
#define HD   128         // hidden dim
#define BB   64          // batch (graphs)
#define NPG  2048        // nodes per graph
#define JTOT 4096        // 2*NPG (concat width)

__device__ __forceinline__ float fast_tanh(float y) {
    // tanh(y) = 1 - 2/(1+exp(2y)); saturates correctly for |y| large.
    float e = __expf(2.0f * y);
    return 1.0f - __fdividef(2.0f, 1.0f + e);
}

// Pass 1: agg1[dst] += x[src]; deg[dst] += 1
__global__ __launch_bounds__(256)
void edge_pass1(const float* __restrict__ x, const int* __restrict__ src,
                const int* __restrict__ dst, float* __restrict__ agg1,
                float* __restrict__ degf) {
    int e = blockIdx.x * blockDim.x + threadIdx.x;
    int stride = gridDim.x * blockDim.x;
    for (; e < ET; e += stride) {
        int s = src[e], d = dst[e];
        atomicAdd(&agg1[d], x[s]);
        atomicAdd(&degf[d], 1.0f);
    }
}

// Per-node: a[v] = h1[v,:]@W2_self, c[v] = h1[v,:]@W2_neigh
// where h1[v,h] = tanh(x[v]*W1s[h] + neigh1[v]*W1n[h] + b1[h])
__global__ __launch_bounds__(256)
void node_pass(const float* __restrict__ x, const float* __restrict__ agg1,
               const float* __restrict__ degf,
               const float* __restrict__ W1s, const float* __restrict__ W1n,
               const float* __restrict__ b1,
               const float* __restrict__ W2s, const float* __restrict__ W2n,
               float* __restrict__ aOut, float* __restrict__ cOut) {
    int v = blockIdx.x * blockDim.x + threadIdx.x;
    if (v >= NT) return;
    float xv = x[v];
    float dg = degf[v];
    dg = dg > 1.0f ? dg : 1.0f;
    float nb = __fdividef(agg1[v], dg);
    float a = 0.0f, c = 0.0f;
#pragma unroll 8
    for (int h = 0; h < HD; ++h) {
        float y = fmaf(xv, W1s[h], fmaf(nb, W1n[h], b1[h]));
        float t = fast_tanh(y);
        a = fmaf(t, W2s[h], a);
        c = fmaf(t, W2n[h], c);
    }
    aOut[v] = a;
    cOut[v] = c;
}

// Pass 2: agg2[dst] += c[src]
__global__ __launch_bounds__(256)
void edge_pass2(const float* __restrict__ c, const int* __restrict__ src,
                const int* __restrict__ dst, float* __restrict__ agg2) {
    int e = blockIdx.x * blockDim.x + threadIdx.x;
    int stride = gridDim.x * blockDim.x;
    for (; e < ET; e += stride) {
        int s = src[e], d = dst[e];
        atomicAdd(&agg2[d], c[s]);
    }
}

// out1[v] = a[v] + agg2[v]/max(deg,1) + b2; h2 = tanh(concat(out1, x)) per graph
__global__ __launch_bounds__(256)
void finalize_k(const float* __restrict__ aA, const float* __restrict__ agg2,
                const float* __restrict__ degf, const float* __restrict__ x,
                const float* __restrict__ b2, float* __restrict__ out1,
                float* __restrict__ h2) {
    int v = blockIdx.x * blockDim.x + threadIdx.x;
    if (v >= NT) return;
    float dg = degf[v];
    dg = dg > 1.0f ? dg : 1.0f;
    float o1 = aA[v] + __fdividef(agg2[v], dg) + b2[0];
    out1[v] = o1;
    int b = v >> 11;          // v / 2048
    int j = v & (NPG - 1);    // v % 2048
    h2[b * JTOT + j] = fast_tanh(o1);
    h2[b * JTOT + NPG + j] = fast_tanh(x[v]);
}

// Split-K partial GEMM: part[kc][b][n] = sum_{j in chunk kc} h2[b][j]*W3[j][n]
// grid = (2048/256, ks); block = 256. W3 read exactly once (coalesced).
__global__ __launch_bounds__(256)
void gemm_partial(const float* __restrict__ h2, const float* __restrict__ W3,
                  float* __restrict__ part, int kchunk) {
    int n = blockIdx.x * 256 + threadIdx.x;   // 0..2047
    int kc = blockIdx.y;
    int j0 = kc * kchunk;
    float acc[BB];
#pragma unroll
    for (int b = 0; b < BB; ++b) acc[b] = 0.0f;
    for (int j = j0; j < j0 + kchunk; j += 4) {
        float w0 = W3[(size_t)(j + 0) * NPG + n];
        float w1 = W3[(size_t)(j + 1) * NPG + n];
        float w2 = W3[(size_t)(j + 2) * NPG + n];
        float w3 = W3[(size_t)(j + 3) * NPG + n];
#pragma unroll
        for (int b = 0; b < BB; ++b) {
            const float4 hv = *reinterpret_cast<const float4*>(&h2[b * JTOT + j]);
            acc[b] = fmaf(hv.x, w0,
                     fmaf(hv.y, w1,
                     fmaf(hv.z, w2,
                     fmaf(hv.w, w3, acc[b]))));
        }
    }
    float* p = part + (size_t)kc * (BB * NPG) + n;
#pragma unroll
    for (int b = 0; b < BB; ++b) p[b * NPG] = acc[b];
}

// out2[b][n] = b3[n] + sum_k part[k][b][n]
__global__ __launch_bounds__(256)
void reduce_out2(const float* __restrict__ part, const float* __restrict__ b3,
                 float* __restrict__ out2, int ks) {
    int i = blockIdx.x * blockDim.x + threadIdx.x;  // b*2048 + n
    if (i >= BB * NPG) return;
    int n = i & (NPG - 1);
    float s = b3[n];
    for (int k = 0; k < ks; ++k) s += part[(size_t)k * (BB * NPG) + i];
    out2[i] = s;
}

extern "C" void kernel_launch(void* const* d_in, const int* in_sizes, int n_in,
                              void* d_out, int out_size, void* d_ws, size_t ws_size,
                              hipStream_t stream) {
    const float* x   = (const float*)d_in[0];
    const int*   src = (const int*)d_in[1];
    const int*   dst = (const int*)d_in[2];
    const float* W1s = (const float*)d_in[3];
    const float* W1n = (const float*)d_in[4];
    const float* b1  = (const float*)d_in[5];
    const float* W2s = (const float*)d_in[6];
    const float* W2n = (const float*)d_in[7];
    const float* b2  = (const float*)d_in[8];
    const float* W3  = (const float*)d_in[9];
    const float* b3  = (const float*)d_in[10];

    float* out1 = (float*)d_out;            // NT elements
    float* out2 = (float*)d_out + NT;       // BB*NPG elements

    float* w    = (float*)d_ws;
    float* agg1 = w;                        // NT
    float* degf = w + (size_t)NT;           // NT
    float* agg2 = w + 2 * (size_t)NT;       // NT
    float* aA   = w + 3 * (size_t)NT;       // NT
    float* cC   = w + 4 * (size_t)NT;       // NT
    float* h2   = w + 5 * (size_t)NT;       // BB*JTOT = 262144
    float* part = h2 + (size_t)BB * JTOT;

    size_t used_bytes = (5 * (size_t)NT + (size_t)BB * JTOT) * sizeof(float);
    int ks = 32;
    while (ks > 1 && used_bytes + (size_t)ks * BB * NPG * sizeof(float) > ws_size)
        ks >>= 1;
    int kchunk = JTOT / ks;

    // zero agg1, degf, agg2 (contiguous 3*NT floats)
    hipMemsetAsync(agg1, 0, 3 * (size_t)NT * sizeof(float), stream);

    edge_pass1<<<4096, 256, 0, stream>>>(x, src, dst, agg1, degf);
    node_pass<<<NT / 256, 256, 0, stream>>>(x, agg1, degf, W1s, W1n, b1, W2s, W2n, aA, cC);
    edge_pass2<<<4096, 256, 0, stream>>>(cC, src, dst, agg2);
    finalize_k<<<NT / 256, 256, 0, stream>>>(aA, agg2, degf, x, b2, out1, h2);
    gemm_partial<<<dim3(NPG / 256, ks), 256, 0, stream>>>(h2, W3, part, kchunk);
    reduce_out2<<<(BB * NPG + 255) / 256, 256, 0, stream>>>(part, b3, out2, ks);
}

// Round 4
// 461.013 us; speedup vs baseline: 1.2326x; 1.2326x over previous
//
#include <hip/hip_runtime.h>

// Problem constants (fixed by the reference).
#define NT   131072      // total nodes
#define ET   2097152     // edges
#define HD   128         // hidden dim
#define BB   64          // batch (graphs)
#define NPG  2048        // nodes per graph
#define JTOT 4096        // 2*NPG (concat width)

#define PK   4294967296.0   // 2^32: degree increment in packed f64 atomic

__device__ __forceinline__ float fast_tanh(float y) {
    float e = __expf(2.0f * y);
    return 1.0f - __fdividef(2.0f, 1.0f + e);
}

// Pass 1: pack[dst] += (double)x[src] + 2^32   (sum in low part, degree in high bits)
// Native fire-and-forget f64 atomic: one fabric transaction per edge instead of two.
__global__ __launch_bounds__(256)
void edge_pass1(const float* __restrict__ x, const int4* __restrict__ src4,
                const int4* __restrict__ dst4, double* __restrict__ pack) {
    int i = blockIdx.x * 256 + threadIdx.x;          // 0 .. ET/4-1
    int4 s = src4[i];
    int4 d = dst4[i];
    unsafeAtomicAdd(&pack[d.x], (double)x[s.x] + PK);
    unsafeAtomicAdd(&pack[d.y], (double)x[s.y] + PK);
    unsafeAtomicAdd(&pack[d.z], (double)x[s.z] + PK);
    unsafeAtomicAdd(&pack[d.w], (double)x[s.w] + PK);
}

__device__ __forceinline__ void unpack(double pv, float& deg, float& sum) {
    double degd = floor(pv * (1.0 / PK) + 0.5);      // |sum| << 2^31, so rounding is exact
    deg = (float)degd;
    sum = (float)(pv - degd * PK);
}

// Per-node: a[v] = h1[v,:]@W2_self, c[v] = h1[v,:]@W2_neigh
__global__ __launch_bounds__(256)
void node_pass(const float* __restrict__ x, const double* __restrict__ pack,
               const float* __restrict__ W1s, const float* __restrict__ W1n,
               const float* __restrict__ b1,
               const float* __restrict__ W2s, const float* __restrict__ W2n,
               float* __restrict__ aOut, float* __restrict__ cOut) {
    int v = blockIdx.x * blockDim.x + threadIdx.x;
    if (v >= NT) return;
    float xv = x[v];
    float dg, sm;
    unpack(pack[v], dg, sm);
    dg = dg > 1.0f ? dg : 1.0f;
    float nb = __fdividef(sm, dg);
    float a = 0.0f, c = 0.0f;
#pragma unroll 8
    for (int h = 0; h < HD; ++h) {
        float y = fmaf(xv, W1s[h], fmaf(nb, W1n[h], b1[h]));
        float t = fast_tanh(y);
        a = fmaf(t, W2s[h], a);
        c = fmaf(t, W2n[h], c);
    }
    aOut[v] = a;
    cOut[v] = c;
}

// Pass 2: agg2[dst] += c[src]  (native f32 atomic)
__global__ __launch_bounds__(256)
void edge_pass2(const float* __restrict__ c, const int4* __restrict__ src4,
                const int4* __restrict__ dst4, float* __restrict__ agg2) {
    int i = blockIdx.x * 256 + threadIdx.x;
    int4 s = src4[i];
    int4 d = dst4[i];
    unsafeAtomicAdd(&agg2[d.x], c[s.x]);
    unsafeAtomicAdd(&agg2[d.y], c[s.y]);
    unsafeAtomicAdd(&agg2[d.z], c[s.z]);
    unsafeAtomicAdd(&agg2[d.w], c[s.w]);
}

// out1[v] = a[v] + agg2[v]/max(deg,1) + b2; h2 = tanh(concat(out1, x)) per graph
__global__ __launch_bounds__(256)
void finalize_k(const float* __restrict__ aA, const float* __restrict__ agg2,
                const double* __restrict__ pack, const float* __restrict__ x,
                const float* __restrict__ b2, float* __restrict__ out1,
                float* __restrict__ h2) {
    int v = blockIdx.x * blockDim.x + threadIdx.x;
    if (v >= NT) return;
    float dg, sm;
    unpack(pack[v], dg, sm);
    dg = dg > 1.0f ? dg : 1.0f;
    float o1 = aA[v] + __fdividef(agg2[v], dg) + b2[0];
    out1[v] = o1;
    int b = v >> 11;          // v / 2048
    int j = v & (NPG - 1);    // v % 2048
    h2[b * JTOT + j] = fast_tanh(o1);
    h2[b * JTOT + NPG + j] = fast_tanh(x[v]);
}

// Split-K partial GEMM: part[kc][b][n] = sum_{j in chunk kc} h2[b][j]*W3[j][n]
__global__ __launch_bounds__(256)
void gemm_partial(const float* __restrict__ h2, const float* __restrict__ W3,
                  float* __restrict__ part, int kchunk) {
    int n = blockIdx.x * 256 + threadIdx.x;   // 0..2047
    int kc = blockIdx.y;
    int j0 = kc * kchunk;
    float acc[BB];
#pragma unroll
    for (int b = 0; b < BB; ++b) acc[b] = 0.0f;
    for (int j = j0; j < j0 + kchunk; j += 4) {
        float w0 = W3[(size_t)(j + 0) * NPG + n];
        float w1 = W3[(size_t)(j + 1) * NPG + n];
        float w2 = W3[(size_t)(j + 2) * NPG + n];
        float w3 = W3[(size_t)(j + 3) * NPG + n];
#pragma unroll
        for (int b = 0; b < BB; ++b) {
            const float4 hv = *reinterpret_cast<const float4*>(&h2[b * JTOT + j]);
            acc[b] = fmaf(hv.x, w0,
                     fmaf(hv.y, w1,
                     fmaf(hv.z, w2,
                     fmaf(hv.w, w3, acc[b]))));
        }
    }
    float* p = part + (size_t)kc * (BB * NPG) + n;
#pragma unroll
    for (int b = 0; b < BB; ++b) p[b * NPG] = acc[b];
}

// out2[b][n] = b3[n] + sum_k part[k][b][n]
__global__ __launch_bounds__(256)
void reduce_out2(const float* __restrict__ part, const float* __restrict__ b3,
                 float* __restrict__ out2, int ks) {
    int i = blockIdx.x * blockDim.x + threadIdx.x;  // b*2048 + n
    if (i >= BB * NPG) return;
    int n = i & (NPG - 1);
    float s = b3[n];
    for (int k = 0; k < ks; ++k) s += part[(size_t)k * (BB * NPG) + i];
    out2[i] = s;
}

extern "C" void kernel_launch(void* const* d_in, const int* in_sizes, int n_in,
                              void* d_out, int out_size, void* d_ws, size_t ws_size,
                              hipStream_t stream) {
    const float* x   = (const float*)d_in[0];
    const int*   src = (const int*)d_in[1];
    const int*   dst = (const int*)d_in[2];
    const float* W1s = (const float*)d_in[3];
    const float* W1n = (const float*)d_in[4];
    const float* b1  = (const float*)d_in[5];
    const float* W2s = (const float*)d_in[6];
    const float* W2n = (const float*)d_in[7];
    const float* b2  = (const float*)d_in[8];
    const float* W3  = (const float*)d_in[9];
    const float* b3  = (const float*)d_in[10];

    float* out1 = (float*)d_out;            // NT elements
    float* out2 = (float*)d_out + NT;       // BB*NPG elements

    // Workspace layout (pack first so the zeroing memset is one contiguous range).
    double* pack = (double*)d_ws;                       // NT doubles (1 MB)
    float*  agg2 = (float*)(pack + NT);                 // NT floats (512 KB)
    float*  aA   = agg2 + NT;
    float*  cC   = aA + NT;
    float*  h2   = cC + NT;                             // BB*JTOT
    float*  part = h2 + (size_t)BB * JTOT;

    size_t used_bytes = (size_t)NT * 8 + ((size_t)3 * NT + (size_t)BB * JTOT) * 4;
    int ks = 32;
    while (ks > 1 && used_bytes + (size_t)ks * BB * NPG * sizeof(float) > ws_size)
        ks >>= 1;
    int kchunk = JTOT / ks;

    // zero pack + agg2 (contiguous)
    hipMemsetAsync(pack, 0, (size_t)NT * 8 + (size_t)NT * 4, stream);

    const int4* src4 = (const int4*)src;
    const int4* dst4 = (const int4*)dst;

    edge_pass1<<<ET / 1024, 256, 0, stream>>>(x, src4, dst4, pack);
    node_pass<<<NT / 256, 256, 0, stream>>>(x, pack, W1s, W1n, b1, W2s, W2n, aA, cC);
    edge_pass2<<<ET / 1024, 256, 0, stream>>>(cC, src4, dst4, agg2);
    finalize_k<<<NT / 256, 256, 0, stream>>>(aA, agg2, pack, x, b2, out1, h2);
    gemm_partial<<<dim3(NPG / 256, ks), 256, 0, stream>>>(h2, W3, part, kchunk);
    reduce_out2<<<(BB * NPG + 255) / 256, 256, 0, stream>>>(part, b3, out2, ks);
}

// Round 5
// 371.469 us; speedup vs baseline: 1.5298x; 1.2411x over previous
//
#include <hip/hip_runtime.h>

// Problem constants (fixed by the reference).
#define NT   131072      // total nodes
#define ET   2097152     // edges
#define HD   128         // hidden dim
#define BB   64          // batch (graphs)
#define NPG  2048        // nodes per graph
#define JTOT 4096        // 2*NPG (concat width)
#define KS   32          // split-K chunks (part = 16 MB, verified to fit ws)
#define KC   (JTOT / KS) // 128 j's per chunk

#define PK   4294967296.0   // 2^32: degree increment in packed f64 atomic

__device__ __forceinline__ float fast_tanh(float y) {
    float e = __expf(2.0f * y);
    return 1.0f - __fdividef(2.0f, 1.0f + e);
}

// Pass 1: pack[dst] += (double)x[src] + 2^32   (sum in low part, degree in high bits)
__global__ __launch_bounds__(256)
void edge_pass1(const float* __restrict__ x, const int4* __restrict__ src4,
                const int4* __restrict__ dst4, double* __restrict__ pack) {
    int i = blockIdx.x * 256 + threadIdx.x;          // 0 .. ET/4-1
    int4 s = src4[i];
    int4 d = dst4[i];
    unsafeAtomicAdd(&pack[d.x], (double)x[s.x] + PK);
    unsafeAtomicAdd(&pack[d.y], (double)x[s.y] + PK);
    unsafeAtomicAdd(&pack[d.z], (double)x[s.z] + PK);
    unsafeAtomicAdd(&pack[d.w], (double)x[s.w] + PK);
}

__device__ __forceinline__ void unpack(double pv, float& deg, float& sum) {
    double degd = floor(pv * (1.0 / PK) + 0.5);      // |sum| << 2^31, rounding exact
    deg = (float)degd;
    sum = (float)(pv - degd * PK);
}

// Per-node: a[v] = h1[v,:]@W2_self, c[v] = h1[v,:]@W2_neigh
__global__ __launch_bounds__(256)
void node_pass(const float* __restrict__ x, const double* __restrict__ pack,
               const float* __restrict__ W1s, const float* __restrict__ W1n,
               const float* __restrict__ b1,
               const float* __restrict__ W2s, const float* __restrict__ W2n,
               float* __restrict__ aOut, float* __restrict__ cOut) {
    int v = blockIdx.x * blockDim.x + threadIdx.x;
    if (v >= NT) return;
    float xv = x[v];
    float dg, sm;
    unpack(pack[v], dg, sm);
    dg = dg > 1.0f ? dg : 1.0f;
    float nb = __fdividef(sm, dg);
    float a = 0.0f, c = 0.0f;
#pragma unroll 8
    for (int h = 0; h < HD; ++h) {
        float y = fmaf(xv, W1s[h], fmaf(nb, W1n[h], b1[h]));
        float t = fast_tanh(y);
        a = fmaf(t, W2s[h], a);
        c = fmaf(t, W2n[h], c);
    }
    aOut[v] = a;
    cOut[v] = c;
}

// Pass 2: agg2[dst] += c[src]  (native f32 atomic)
__global__ __launch_bounds__(256)
void edge_pass2(const float* __restrict__ c, const int4* __restrict__ src4,
                const int4* __restrict__ dst4, float* __restrict__ agg2) {
    int i = blockIdx.x * 256 + threadIdx.x;
    int4 s = src4[i];
    int4 d = dst4[i];
    unsafeAtomicAdd(&agg2[d.x], c[s.x]);
    unsafeAtomicAdd(&agg2[d.y], c[s.y]);
    unsafeAtomicAdd(&agg2[d.z], c[s.z]);
    unsafeAtomicAdd(&agg2[d.w], c[s.w]);
}

// out1[v] = a[v] + agg2[v]/max(deg,1) + b2; h2 = tanh(concat(out1, x)) per graph
__global__ __launch_bounds__(256)
void finalize_k(const float* __restrict__ aA, const float* __restrict__ agg2,
                const double* __restrict__ pack, const float* __restrict__ x,
                const float* __restrict__ b2, float* __restrict__ out1,
                float* __restrict__ h2) {
    int v = blockIdx.x * blockDim.x + threadIdx.x;
    if (v >= NT) return;
    float dg, sm;
    unpack(pack[v], dg, sm);
    dg = dg > 1.0f ? dg : 1.0f;
    float o1 = aA[v] + __fdividef(agg2[v], dg) + b2[0];
    out1[v] = o1;
    int b = v >> 11;          // v / 2048
    int j = v & (NPG - 1);    // v % 2048
    h2[b * JTOT + j] = fast_tanh(o1);
    h2[b * JTOT + NPG + j] = fast_tanh(x[v]);
}

// Register-tiled split-K GEMM.
// Block = 256 threads = (8 batch-groups) x (32 col-groups).
// Block tile: all 64 batches x 128 cols x KC=128 K-slice. W3 read EXACTLY once.
// Thread: 8 batches x 4 cols = 32 accumulators, float4 loads on both operands.
// grid = (2048/128 = 16, KS = 32) = 512 blocks.
__global__ __launch_bounds__(256)
void gemm_partial(const float* __restrict__ h2, const float* __restrict__ W3,
                  float* __restrict__ part) {
    const int cg = threadIdx.x & 31;   // col group 0..31
    const int bg = threadIdx.x >> 5;   // batch group 0..7
    const int n0 = blockIdx.x * 128 + cg * 4;
    const int j0 = blockIdx.y * KC;

    const float* W3p = W3 + (size_t)j0 * NPG + n0;
    const float* h2p = h2 + (size_t)(bg * 8) * JTOT + j0;

    float acc[8][4];
#pragma unroll
    for (int b = 0; b < 8; ++b)
#pragma unroll
        for (int q = 0; q < 4; ++q) acc[b][q] = 0.0f;

    for (int jj = 0; jj < KC; jj += 4) {
        const float4 w0 = *reinterpret_cast<const float4*>(&W3p[(size_t)(jj + 0) * NPG]);
        const float4 w1 = *reinterpret_cast<const float4*>(&W3p[(size_t)(jj + 1) * NPG]);
        const float4 w2 = *reinterpret_cast<const float4*>(&W3p[(size_t)(jj + 2) * NPG]);
        const float4 w3 = *reinterpret_cast<const float4*>(&W3p[(size_t)(jj + 3) * NPG]);
#pragma unroll
        for (int b = 0; b < 8; ++b) {
            const float4 hv = *reinterpret_cast<const float4*>(&h2p[b * JTOT + jj]);
            acc[b][0] = fmaf(hv.x, w0.x, fmaf(hv.y, w1.x, fmaf(hv.z, w2.x, fmaf(hv.w, w3.x, acc[b][0]))));
            acc[b][1] = fmaf(hv.x, w0.y, fmaf(hv.y, w1.y, fmaf(hv.z, w2.y, fmaf(hv.w, w3.y, acc[b][1]))));
            acc[b][2] = fmaf(hv.x, w0.z, fmaf(hv.y, w1.z, fmaf(hv.z, w2.z, fmaf(hv.w, w3.z, acc[b][2]))));
            acc[b][3] = fmaf(hv.x, w0.w, fmaf(hv.y, w1.w, fmaf(hv.z, w2.w, fmaf(hv.w, w3.w, acc[b][3]))));
        }
    }

    float* p = part + ((size_t)blockIdx.y * BB + bg * 8) * NPG + n0;
#pragma unroll
    for (int b = 0; b < 8; ++b) {
        float4 r;
        r.x = acc[b][0]; r.y = acc[b][1]; r.z = acc[b][2]; r.w = acc[b][3];
        *reinterpret_cast<float4*>(&p[(size_t)b * NPG]) = r;
    }
}

// out2[b][n] = b3[n] + sum_k part[k][b][n]
__global__ __launch_bounds__(256)
void reduce_out2(const float* __restrict__ part, const float* __restrict__ b3,
                 float* __restrict__ out2) {
    int i = blockIdx.x * blockDim.x + threadIdx.x;  // b*2048 + n
    if (i >= BB * NPG) return;
    int n = i & (NPG - 1);
    float s = b3[n];
#pragma unroll
    for (int k = 0; k < KS; ++k) s += part[(size_t)k * (BB * NPG) + i];
    out2[i] = s;
}

extern "C" void kernel_launch(void* const* d_in, const int* in_sizes, int n_in,
                              void* d_out, int out_size, void* d_ws, size_t ws_size,
                              hipStream_t stream) {
    const float* x   = (const float*)d_in[0];
    const int*   src = (const int*)d_in[1];
    const int*   dst = (const int*)d_in[2];
    const float* W1s = (const float*)d_in[3];
    const float* W1n = (const float*)d_in[4];
    const float* b1  = (const float*)d_in[5];
    const float* W2s = (const float*)d_in[6];
    const float* W2n = (const float*)d_in[7];
    const float* b2  = (const float*)d_in[8];
    const float* W3  = (const float*)d_in[9];
    const float* b3  = (const float*)d_in[10];

    float* out1 = (float*)d_out;            // NT elements
    float* out2 = (float*)d_out + NT;       // BB*NPG elements

    // Workspace layout (pack first so the zeroing memset is one contiguous range).
    double* pack = (double*)d_ws;                       // NT doubles (1 MB)
    float*  agg2 = (float*)(pack + NT);                 // NT floats (512 KB)
    float*  aA   = agg2 + NT;
    float*  cC   = aA + NT;
    float*  h2   = cC + NT;                             // BB*JTOT
    float*  part = h2 + (size_t)BB * JTOT;              // KS*BB*NPG = 16 MB

    // zero pack + agg2 (contiguous)
    hipMemsetAsync(pack, 0, (size_t)NT * 8 + (size_t)NT * 4, stream);

    const int4* src4 = (const int4*)src;
    const int4* dst4 = (const int4*)dst;

    edge_pass1<<<ET / 1024, 256, 0, stream>>>(x, src4, dst4, pack);
    node_pass<<<NT / 256, 256, 0, stream>>>(x, pack, W1s, W1n, b1, W2s, W2n, aA, cC);
    edge_pass2<<<ET / 1024, 256, 0, stream>>>(cC, src4, dst4, agg2);
    finalize_k<<<NT / 256, 256, 0, stream>>>(aA, agg2, pack, x, b2, out1, h2);
    gemm_partial<<<dim3(NPG / 128, KS), 256, 0, stream>>>(h2, W3, part);
    reduce_out2<<<(BB * NPG + 255) / 256, 256, 0, stream>>>(part, b3, out2);
}

// Round 8
// 281.379 us; speedup vs baseline: 2.0196x; 1.3202x over previous
//
#include <hip/hip_runtime.h>
#include <stdint.h>

// Problem constants (fixed by the reference).
#define NT   131072      // total nodes
#define ET   2097152     // edges
#define QT   (ET / 4)    // int4 quads
#define HD   128         // hidden dim
#define BB   64          // batch (graphs)
#define NPG  2048        // nodes per graph
#define JTOT 4096        // 2*NPG (concat width)
#define KS   32          // split-K chunks for final GEMM
#define KC   (JTOT / KS)

#define RNG  16384       // nodes per LDS range (64 KB accumulator -> 2 blocks/CU)
#define NR   (NT / RNG)  // 8 ranges
#define DEGU 41943040u   // 2^25 + 2^23: packed degree unit (sum field |.| << this)

__device__ __forceinline__ float fast_tanh(float y) {
    float e = __expf(2.0f * y);
    return 1.0f - __fdividef(2.0f, 1.0f + e);
}

// ---- Pass 1: per (edge-slice m, range r) block: LDS-accumulate packed (deg, sum_x).
// Packed u32: T = deg*DEGU + round(x*2^16) summed mod 2^32 (stays positive; deg<=~50).
__global__ __launch_bounds__(256)
void edge_bin1(const float* __restrict__ x, const int4* __restrict__ src4,
               const int4* __restrict__ dst4, uint32_t* __restrict__ P1, int qpb) {
    __shared__ uint32_t acc[RNG];
    for (int i = threadIdx.x; i < RNG; i += 256) acc[i] = 0u;
    __syncthreads();
    const int base = blockIdx.y * RNG;
    int q0 = blockIdx.x * qpb;
    int q1 = q0 + qpb; if (q1 > QT) q1 = QT;
    for (int q = q0 + threadIdx.x; q < q1; q += 256) {
        int4 d = dst4[q];
        int4 s = src4[q];
        unsigned l;
        l = (unsigned)(d.x - base);
        if (l < RNG) __hip_atomic_fetch_add(&acc[l], DEGU + (uint32_t)(int)rintf(x[s.x] * 65536.0f),
                                            __ATOMIC_RELAXED, __HIP_MEMORY_SCOPE_WORKGROUP);
        l = (unsigned)(d.y - base);
        if (l < RNG) __hip_atomic_fetch_add(&acc[l], DEGU + (uint32_t)(int)rintf(x[s.y] * 65536.0f),
                                            __ATOMIC_RELAXED, __HIP_MEMORY_SCOPE_WORKGROUP);
        l = (unsigned)(d.z - base);
        if (l < RNG) __hip_atomic_fetch_add(&acc[l], DEGU + (uint32_t)(int)rintf(x[s.z] * 65536.0f),
                                            __ATOMIC_RELAXED, __HIP_MEMORY_SCOPE_WORKGROUP);
        l = (unsigned)(d.w - base);
        if (l < RNG) __hip_atomic_fetch_add(&acc[l], DEGU + (uint32_t)(int)rintf(x[s.w] * 65536.0f),
                                            __ATOMIC_RELAXED, __HIP_MEMORY_SCOPE_WORKGROUP);
    }
    __syncthreads();
    uint32_t* o = P1 + (size_t)blockIdx.x * NT + base;
    for (int i = threadIdx.x; i < RNG; i += 256) o[i] = acc[i];
}

// ---- Per-node: sum M packed partials, unpack (deg, sum), compute
// a[v] = h1[v,:]@W2_self, c[v] = h1[v,:]@W2_neigh, and dInv[v] = 1/max(deg,1).
__global__ __launch_bounds__(256)
void node_pass(const float* __restrict__ x, const uint32_t* __restrict__ P1, int M,
               const float* __restrict__ W1s, const float* __restrict__ W1n,
               const float* __restrict__ b1,
               const float* __restrict__ W2s, const float* __restrict__ W2n,
               float* __restrict__ aOut, float* __restrict__ cOut,
               float* __restrict__ dInv) {
    int v = blockIdx.x * blockDim.x + threadIdx.x;
    if (v >= NT) return;
    uint32_t T = 0u;
    for (int m = 0; m < M; ++m) T += P1[(size_t)m * NT + v];
    float degf = rintf((float)T * (1.0f / (float)DEGU));
    uint32_t degu = (uint32_t)degf;
    int rem = (int)(T - degu * DEGU);
    float sm = (float)rem * (1.0f / 65536.0f);
    float dg = degf > 1.0f ? degf : 1.0f;
    float di = __fdividef(1.0f, dg);
    dInv[v] = di;
    float nb = sm * di;
    float xv = x[v];
    float a = 0.0f, c = 0.0f;
#pragma unroll 8
    for (int h = 0; h < HD; ++h) {
        float y = fmaf(xv, W1s[h], fmaf(nb, W1n[h], b1[h]));
        float t = fast_tanh(y);
        a = fmaf(t, W2s[h], a);
        c = fmaf(t, W2n[h], c);
    }
    aOut[v] = a;
    cOut[v] = c;
}

// ---- Pass 2: same structure, f32 LDS accumulate of c[src].
__global__ __launch_bounds__(256)
void edge_bin2(const float* __restrict__ c, const int4* __restrict__ src4,
               const int4* __restrict__ dst4, float* __restrict__ P2, int qpb) {
    __shared__ float acc[RNG];
    for (int i = threadIdx.x; i < RNG; i += 256) acc[i] = 0.0f;
    __syncthreads();
    const int base = blockIdx.y * RNG;
    int q0 = blockIdx.x * qpb;
    int q1 = q0 + qpb; if (q1 > QT) q1 = QT;
    for (int q = q0 + threadIdx.x; q < q1; q += 256) {
        int4 d = dst4[q];
        int4 s = src4[q];
        unsigned l;
        l = (unsigned)(d.x - base);
        if (l < RNG) __hip_atomic_fetch_add(&acc[l], c[s.x], __ATOMIC_RELAXED, __HIP_MEMORY_SCOPE_WORKGROUP);
        l = (unsigned)(d.y - base);
        if (l < RNG) __hip_atomic_fetch_add(&acc[l], c[s.y], __ATOMIC_RELAXED, __HIP_MEMORY_SCOPE_WORKGROUP);
        l = (unsigned)(d.z - base);
        if (l < RNG) __hip_atomic_fetch_add(&acc[l], c[s.z], __ATOMIC_RELAXED, __HIP_MEMORY_SCOPE_WORKGROUP);
        l = (unsigned)(d.w - base);
        if (l < RNG) __hip_atomic_fetch_add(&acc[l], c[s.w], __ATOMIC_RELAXED, __HIP_MEMORY_SCOPE_WORKGROUP);
    }
    __syncthreads();
    float* o = P2 + (size_t)blockIdx.x * NT + base;
    for (int i = threadIdx.x; i < RNG; i += 256) o[i] = acc[i];
}

// ---- out1[v] = a[v] + (sum_m P2)/max(deg,1) + b2; h2 = tanh(concat(out1, x)).
__global__ __launch_bounds__(256)
void finalize_k(const float* __restrict__ aA, const float* __restrict__ P2, int M,
                const float* __restrict__ dInv, const float* __restrict__ x,
                const float* __restrict__ b2, float* __restrict__ out1,
                float* __restrict__ h2) {
    int v = blockIdx.x * blockDim.x + threadIdx.x;
    if (v >= NT) return;
    float s2 = 0.0f;
    for (int m = 0; m < M; ++m) s2 += P2[(size_t)m * NT + v];
    float o1 = fmaf(s2, dInv[v], aA[v] + b2[0]);
    out1[v] = o1;
    int b = v >> 11;          // v / 2048
    int j = v & (NPG - 1);    // v % 2048
    h2[b * JTOT + j] = fast_tanh(o1);
    h2[b * JTOT + NPG + j] = fast_tanh(x[v]);
}

// ---- Register-tiled split-K GEMM (unchanged from round 5).
__global__ __launch_bounds__(256)
void gemm_partial(const float* __restrict__ h2, const float* __restrict__ W3,
                  float* __restrict__ part) {
    const int cg = threadIdx.x & 31;
    const int bg = threadIdx.x >> 5;
    const int n0 = blockIdx.x * 128 + cg * 4;
    const int j0 = blockIdx.y * KC;

    const float* W3p = W3 + (size_t)j0 * NPG + n0;
    const float* h2p = h2 + (size_t)(bg * 8) * JTOT + j0;

    float acc[8][4];
#pragma unroll
    for (int b = 0; b < 8; ++b)
#pragma unroll
        for (int q = 0; q < 4; ++q) acc[b][q] = 0.0f;

    for (int jj = 0; jj < KC; jj += 4) {
        const float4 w0 = *reinterpret_cast<const float4*>(&W3p[(size_t)(jj + 0) * NPG]);
        const float4 w1 = *reinterpret_cast<const float4*>(&W3p[(size_t)(jj + 1) * NPG]);
        const float4 w2 = *reinterpret_cast<const float4*>(&W3p[(size_t)(jj + 2) * NPG]);
        const float4 w3 = *reinterpret_cast<const float4*>(&W3p[(size_t)(jj + 3) * NPG]);
#pragma unroll
        for (int b = 0; b < 8; ++b) {
            const float4 hv = *reinterpret_cast<const float4*>(&h2p[b * JTOT + jj]);
            acc[b][0] = fmaf(hv.x, w0.x, fmaf(hv.y, w1.x, fmaf(hv.z, w2.x, fmaf(hv.w, w3.x, acc[b][0]))));
            acc[b][1] = fmaf(hv.x, w0.y, fmaf(hv.y, w1.y, fmaf(hv.z, w2.y, fmaf(hv.w, w3.y, acc[b][1]))));
            acc[b][2] = fmaf(hv.x, w0.z, fmaf(hv.y, w1.z, fmaf(hv.z, w2.z, fmaf(hv.w, w3.z, acc[b][2]))));
            acc[b][3] = fmaf(hv.x, w0.w, fmaf(hv.y, w1.w, fmaf(hv.z, w2.w, fmaf(hv.w, w3.w, acc[b][3]))));
        }
    }

    float* p = part + ((size_t)blockIdx.y * BB + bg * 8) * NPG + n0;
#pragma unroll
    for (int b = 0; b < 8; ++b) {
        float4 r;
        r.x = acc[b][0]; r.y = acc[b][1]; r.z = acc[b][2]; r.w = acc[b][3];
        *reinterpret_cast<float4*>(&p[(size_t)b * NPG]) = r;
    }
}

__global__ __launch_bounds__(256)
void reduce_out2(const float* __restrict__ part, const float* __restrict__ b3,
                 float* __restrict__ out2) {
    int i = blockIdx.x * blockDim.x + threadIdx.x;
    if (i >= BB * NPG) return;
    int n = i & (NPG - 1);
    float s = b3[n];
#pragma unroll
    for (int k = 0; k < KS; ++k) s += part[(size_t)k * (BB * NPG) + i];
    out2[i] = s;
}

extern "C" void kernel_launch(void* const* d_in, const int* in_sizes, int n_in,
                              void* d_out, int out_size, void* d_ws, size_t ws_size,
                              hipStream_t stream) {
    const float* x   = (const float*)d_in[0];
    const int*   src = (const int*)d_in[1];
    const int*   dst = (const int*)d_in[2];
    const float* W1s = (const float*)d_in[3];
    const float* W1n = (const float*)d_in[4];
    const float* b1  = (const float*)d_in[5];
    const float* W2s = (const float*)d_in[6];
    const float* W2n = (const float*)d_in[7];
    const float* b2  = (const float*)d_in[8];
    const float* W3  = (const float*)d_in[9];
    const float* b3  = (const float*)d_in[10];

    float* out1 = (float*)d_out;            // NT
    float* out2 = (float*)d_out + NT;       // BB*NPG

    // Workspace: fixed head, then SCRATCH shared sequentially by P1 -> P2 -> part.
    float* aA   = (float*)d_ws;                          // NT
    float* cC   = aA + NT;                               // NT
    float* dInv = cC + NT;                               // NT
    float* h2   = dInv + NT;                             // BB*JTOT (1 MB)
    char*  scratch = (char*)(h2 + (size_t)BB * JTOT);
    size_t head_bytes = ((size_t)3 * NT + (size_t)BB * JTOT) * sizeof(float);
    size_t scratch_bytes = ws_size - head_bytes;

    // M edge-slices: each needs NT*4 bytes of partial. part (16 MB) also lives here.
    int M = (int)(scratch_bytes / ((size_t)NT * 4));
    if (M > 64) M = 64;
    if (M < 1) M = 1;
    int qpb = (QT + M - 1) / M;

    uint32_t* P1   = (uint32_t*)scratch;   // [M][NT]
    float*    P2   = (float*)scratch;      // [M][NT]   (after P1 is dead)
    float*    part = (float*)scratch;      // [KS][BB][NPG] (after P2 is dead)

    edge_bin1<<<dim3(M, NR), 256, 0, stream>>>(x, (const int4*)src, (const int4*)dst, P1, qpb);
    node_pass<<<NT / 256, 256, 0, stream>>>(x, P1, M, W1s, W1n, b1, W2s, W2n, aA, cC, dInv);
    edge_bin2<<<dim3(M, NR), 256, 0, stream>>>(cC, (const int4*)src, (const int4*)dst, P2, qpb);
    finalize_k<<<NT / 256, 256, 0, stream>>>(aA, P2, M, dInv, x, b2, out1, h2);
    gemm_partial<<<dim3(NPG / 128, KS), 256, 0, stream>>>(h2, W3, part);
    reduce_out2<<<(BB * NPG + 255) / 256, 256, 0, stream>>>(part, b3, out2);
}

// Round 9
// 233.504 us; speedup vs baseline: 2.4336x; 1.2050x over previous
//
#include <hip/hip_runtime.h>
#include <stdint.h>

// Problem constants (fixed by the reference).
#define NT   131072      // total nodes
#define ET   2097152     // edges
#define QT   (ET / 4)    // int4 quads
#define HD   128         // hidden dim
#define BB   64          // batch (graphs)
#define NPG  2048        // nodes per graph
#define JTOT 4096        // 2*NPG (concat width)
#define KS   32          // split-K chunks for final GEMM
#define KC   (JTOT / KS) // 128

#define RNG  16384       // nodes per LDS range (64 KB accumulator -> 2 blocks/CU)
#define NR   (NT / RNG)  // 8 ranges
#define DEGU 41943040u   // 2^25 + 2^23: packed degree unit (sum field |.| << this)

typedef __attribute__((ext_vector_type(8))) short bf16x8;
typedef __attribute__((ext_vector_type(4))) float f32x4;

__device__ __forceinline__ float fast_tanh(float y) {
    float e = __expf(2.0f * y);
    return 1.0f - __fdividef(2.0f, 1.0f + e);
}

// f32 -> bf16 bits, round-to-nearest-even.
__device__ __forceinline__ unsigned f2b(float f) {
    union { float f; unsigned u; } v; v.f = f;
    return (v.u + 0x7FFFu + ((v.u >> 16) & 1u)) >> 16;
}

// ---- Pass 1: per (edge-slice m, range r) block: LDS-accumulate packed (deg, sum_x).
__global__ __launch_bounds__(256)
void edge_bin1(const float* __restrict__ x, const int4* __restrict__ src4,
               const int4* __restrict__ dst4, uint32_t* __restrict__ P1, int qpb) {
    __shared__ uint32_t acc[RNG];
    for (int i = threadIdx.x; i < RNG; i += 256) acc[i] = 0u;
    __syncthreads();
    const int base = blockIdx.y * RNG;
    int q0 = blockIdx.x * qpb;
    int q1 = q0 + qpb; if (q1 > QT) q1 = QT;
    for (int q = q0 + threadIdx.x; q < q1; q += 256) {
        int4 d = dst4[q];
        int4 s = src4[q];
        unsigned l;
        l = (unsigned)(d.x - base);
        if (l < RNG) __hip_atomic_fetch_add(&acc[l], DEGU + (uint32_t)(int)rintf(x[s.x] * 65536.0f),
                                            __ATOMIC_RELAXED, __HIP_MEMORY_SCOPE_WORKGROUP);
        l = (unsigned)(d.y - base);
        if (l < RNG) __hip_atomic_fetch_add(&acc[l], DEGU + (uint32_t)(int)rintf(x[s.y] * 65536.0f),
                                            __ATOMIC_RELAXED, __HIP_MEMORY_SCOPE_WORKGROUP);
        l = (unsigned)(d.z - base);
        if (l < RNG) __hip_atomic_fetch_add(&acc[l], DEGU + (uint32_t)(int)rintf(x[s.z] * 65536.0f),
                                            __ATOMIC_RELAXED, __HIP_MEMORY_SCOPE_WORKGROUP);
        l = (unsigned)(d.w - base);
        if (l < RNG) __hip_atomic_fetch_add(&acc[l], DEGU + (uint32_t)(int)rintf(x[s.w] * 65536.0f),
                                            __ATOMIC_RELAXED, __HIP_MEMORY_SCOPE_WORKGROUP);
    }
    __syncthreads();
    uint32_t* o = P1 + (size_t)blockIdx.x * NT + base;
    for (int i = threadIdx.x; i < RNG; i += 256) o[i] = acc[i];
}

// ---- Per-node: sum M packed partials, unpack (deg, sum), compute a, c, 1/deg.
__global__ __launch_bounds__(256)
void node_pass(const float* __restrict__ x, const uint32_t* __restrict__ P1, int M,
               const float* __restrict__ W1s, const float* __restrict__ W1n,
               const float* __restrict__ b1,
               const float* __restrict__ W2s, const float* __restrict__ W2n,
               float* __restrict__ aOut, float* __restrict__ cOut,
               float* __restrict__ dInv) {
    int v = blockIdx.x * blockDim.x + threadIdx.x;
    if (v >= NT) return;
    uint32_t T = 0u;
    for (int m = 0; m < M; ++m) T += P1[(size_t)m * NT + v];
    float degf = rintf((float)T * (1.0f / (float)DEGU));
    uint32_t degu = (uint32_t)degf;
    int rem = (int)(T - degu * DEGU);
    float sm = (float)rem * (1.0f / 65536.0f);
    float dg = degf > 1.0f ? degf : 1.0f;
    float di = __fdividef(1.0f, dg);
    dInv[v] = di;
    float nb = sm * di;
    float xv = x[v];
    float a = 0.0f, c = 0.0f;
#pragma unroll 8
    for (int h = 0; h < HD; ++h) {
        float y = fmaf(xv, W1s[h], fmaf(nb, W1n[h], b1[h]));
        float t = fast_tanh(y);
        a = fmaf(t, W2s[h], a);
        c = fmaf(t, W2n[h], c);
    }
    aOut[v] = a;
    cOut[v] = c;
}

// ---- Pass 2: same structure, f32 LDS accumulate of c[src].
__global__ __launch_bounds__(256)
void edge_bin2(const float* __restrict__ c, const int4* __restrict__ src4,
               const int4* __restrict__ dst4, float* __restrict__ P2, int qpb) {
    __shared__ float acc[RNG];
    for (int i = threadIdx.x; i < RNG; i += 256) acc[i] = 0.0f;
    __syncthreads();
    const int base = blockIdx.y * RNG;
    int q0 = blockIdx.x * qpb;
    int q1 = q0 + qpb; if (q1 > QT) q1 = QT;
    for (int q = q0 + threadIdx.x; q < q1; q += 256) {
        int4 d = dst4[q];
        int4 s = src4[q];
        unsigned l;
        l = (unsigned)(d.x - base);
        if (l < RNG) __hip_atomic_fetch_add(&acc[l], c[s.x], __ATOMIC_RELAXED, __HIP_MEMORY_SCOPE_WORKGROUP);
        l = (unsigned)(d.y - base);
        if (l < RNG) __hip_atomic_fetch_add(&acc[l], c[s.y], __ATOMIC_RELAXED, __HIP_MEMORY_SCOPE_WORKGROUP);
        l = (unsigned)(d.z - base);
        if (l < RNG) __hip_atomic_fetch_add(&acc[l], c[s.z], __ATOMIC_RELAXED, __HIP_MEMORY_SCOPE_WORKGROUP);
        l = (unsigned)(d.w - base);
        if (l < RNG) __hip_atomic_fetch_add(&acc[l], c[s.w], __ATOMIC_RELAXED, __HIP_MEMORY_SCOPE_WORKGROUP);
    }
    __syncthreads();
    float* o = P2 + (size_t)blockIdx.x * NT + base;
    for (int i = threadIdx.x; i < RNG; i += 256) o[i] = acc[i];
}

// ---- out1[v] = a + (sum_m P2)*dInv + b2; h2 (bf16) = tanh(concat(out1, x)).
__global__ __launch_bounds__(256)
void finalize_k(const float* __restrict__ aA, const float* __restrict__ P2, int M,
                const float* __restrict__ dInv, const float* __restrict__ x,
                const float* __restrict__ b2, float* __restrict__ out1,
                unsigned short* __restrict__ h2b) {
    int v = blockIdx.x * blockDim.x + threadIdx.x;
    if (v >= NT) return;
    float s2 = 0.0f;
    for (int m = 0; m < M; ++m) s2 += P2[(size_t)m * NT + v];
    float o1 = fmaf(s2, dInv[v], aA[v] + b2[0]);
    out1[v] = o1;
    int b = v >> 11;          // v / 2048
    int j = v & (NPG - 1);    // v % 2048
    h2b[b * JTOT + j] = (unsigned short)f2b(fast_tanh(o1));
    h2b[b * JTOT + NPG + j] = (unsigned short)f2b(fast_tanh(x[v]));
}

// ---- MFMA split-K GEMM: part[kc] = h2b[64, k-chunk] x W3[k-chunk, 128-col tile].
// A-frag: lane&15 = m-row, lane>>4 = k-octet (8 consecutive k)  [m97-verified layout]
// B-frag: lane&15 = n-col, lane>>4 = k-octet
// C/D:    col = lane&15, row = 4*(lane>>4) + reg                [m89/m91-verified]
__global__ __launch_bounds__(256)
void gemm_mfma(const unsigned short* __restrict__ h2b, const float* __restrict__ W3,
               float* __restrict__ part) {
    __shared__ int4 Al[64 * 17];    // A: 64 rows x 16 chunks(16B=8 bf16), stride 17 (pad)
    __shared__ int4 Bl[16 * 130];   // B^T: 16 k-octets x 128 cols, stride 130 (pad)
    const int t = threadIdx.x;
    const int n0 = blockIdx.x * 128;
    const int k0 = blockIdx.y * KC;

    // stage A: rows 0..63 (= batch), k-window [k0, k0+128)
    {
        const int row = t >> 2;
        const int cb = t & 3;
        const int4* g = (const int4*)(h2b + (size_t)row * JTOT + k0);
#pragma unroll
        for (int i = 0; i < 4; ++i) {
            int cidx = cb + 4 * i;
            Al[row * 17 + cidx] = g[cidx];
        }
    }
    // stage B: W3[k0..+128][n0..+128) f32 -> bf16; Bl[kg][n] holds k = kg*8..+8 of col n
    for (int p = 0; p < 8; ++p) {
        int idx = p * 256 + t;
        int kg = idx >> 7;            // 0..15
        int n  = idx & 127;
        const float* g = W3 + (size_t)(k0 + kg * 8) * NPG + n0 + n;
        unsigned p0 = f2b(g[0 * NPG]) | (f2b(g[1 * NPG]) << 16);
        unsigned p1 = f2b(g[2 * NPG]) | (f2b(g[3 * NPG]) << 16);
        unsigned p2 = f2b(g[4 * NPG]) | (f2b(g[5 * NPG]) << 16);
        unsigned p3 = f2b(g[6 * NPG]) | (f2b(g[7 * NPG]) << 16);
        int4 v; v.x = (int)p0; v.y = (int)p1; v.z = (int)p2; v.w = (int)p3;
        Bl[kg * 130 + n] = v;
    }
    __syncthreads();

    const int lane = t & 63;
    const int w = t >> 6;             // wave 0..3 -> rows [16w, 16w+16)
    const int lr = lane & 15;
    const int lg = lane >> 4;

    f32x4 acc[8];
#pragma unroll
    for (int ct = 0; ct < 8; ++ct) acc[ct] = (f32x4){0.f, 0.f, 0.f, 0.f};

#pragma unroll
    for (int ksb = 0; ksb < 4; ++ksb) {
        bf16x8 a = *(const bf16x8*)&Al[(16 * w + lr) * 17 + ksb * 4 + lg];
#pragma unroll
        for (int ct = 0; ct < 8; ++ct) {
            bf16x8 b = *(const bf16x8*)&Bl[(ksb * 4 + lg) * 130 + 16 * ct + lr];
            acc[ct] = __builtin_amdgcn_mfma_f32_16x16x32_bf16(a, b, acc[ct], 0, 0, 0);
        }
    }

    float* p = part + ((size_t)blockIdx.y * BB) * NPG + n0;
#pragma unroll
    for (int ct = 0; ct < 8; ++ct) {
        int n = 16 * ct + lr;
#pragma unroll
        for (int r = 0; r < 4; ++r) {
            int m = 16 * w + 4 * lg + r;
            p[(size_t)m * NPG + n] = acc[ct][r];
        }
    }
}

__global__ __launch_bounds__(256)
void reduce_out2(const float* __restrict__ part, const float* __restrict__ b3,
                 float* __restrict__ out2) {
    int i = blockIdx.x * blockDim.x + threadIdx.x;
    if (i >= BB * NPG) return;
    int n = i & (NPG - 1);
    float s = b3[n];
#pragma unroll
    for (int k = 0; k < KS; ++k) s += part[(size_t)k * (BB * NPG) + i];
    out2[i] = s;
}

extern "C" void kernel_launch(void* const* d_in, const int* in_sizes, int n_in,
                              void* d_out, int out_size, void* d_ws, size_t ws_size,
                              hipStream_t stream) {
    const float* x   = (const float*)d_in[0];
    const int*   src = (const int*)d_in[1];
    const int*   dst = (const int*)d_in[2];
    const float* W1s = (const float*)d_in[3];
    const float* W1n = (const float*)d_in[4];
    const float* b1  = (const float*)d_in[5];
    const float* W2s = (const float*)d_in[6];
    const float* W2n = (const float*)d_in[7];
    const float* b2  = (const float*)d_in[8];
    const float* W3  = (const float*)d_in[9];
    const float* b3  = (const float*)d_in[10];

    float* out1 = (float*)d_out;            // NT
    float* out2 = (float*)d_out + NT;       // BB*NPG

    // Workspace: fixed head, then SCRATCH shared sequentially by P1 -> P2 -> part.
    float* aA   = (float*)d_ws;                          // NT
    float* cC   = aA + NT;                               // NT
    float* dInv = cC + NT;                               // NT
    unsigned short* h2b = (unsigned short*)(dInv + NT);  // BB*JTOT bf16 (512 KB)
    char*  scratch = (char*)(h2b + (size_t)BB * JTOT);
    size_t head_bytes = (size_t)3 * NT * 4 + (size_t)BB * JTOT * 2;
    size_t scratch_bytes = ws_size - head_bytes;

    int M = (int)(scratch_bytes / ((size_t)NT * 4));
    if (M > 64) M = 64;
    if (M < 1) M = 1;
    int qpb = (QT + M - 1) / M;

    uint32_t* P1   = (uint32_t*)scratch;   // [M][NT]
    float*    P2   = (float*)scratch;      // [M][NT]   (after P1 is dead)
    float*    part = (float*)scratch;      // [KS][BB][NPG] = 16 MB (after P2 is dead)

    edge_bin1<<<dim3(M, NR), 256, 0, stream>>>(x, (const int4*)src, (const int4*)dst, P1, qpb);
    node_pass<<<NT / 256, 256, 0, stream>>>(x, P1, M, W1s, W1n, b1, W2s, W2n, aA, cC, dInv);
    edge_bin2<<<dim3(M, NR), 256, 0, stream>>>(cC, (const int4*)src, (const int4*)dst, P2, qpb);
    finalize_k<<<NT / 256, 256, 0, stream>>>(aA, P2, M, dInv, x, b2, out1, h2b);
    gemm_mfma<<<dim3(NPG / 128, KS), 256, 0, stream>>>(h2b, W3, part);
    reduce_out2<<<(BB * NPG + 255) / 256, 256, 0, stream>>>(part, b3, out2);
}

// Round 12
// 189.430 us; speedup vs baseline: 2.9999x; 1.2327x over previous
//
#include <hip/hip_runtime.h>
#include <stdint.h>

// Problem constants (fixed by the reference).
#define NT   131072      // total nodes
#define ET   2097152     // edges
#define QT   (ET / 4)    // int4 quads
#define HD   128         // hidden dim
#define BB   64          // batch (graphs)
#define NPG  2048        // nodes per graph
#define JTOT 4096        // 2*NPG (concat width)
#define KS   32          // split-K chunks for final GEMM
#define KC   (JTOT / KS) // 128

#define NRB  64          // destination-range buckets
#define RNGB 2048        // nodes per bucket (8 KB LDS accumulator -> 8 blocks/CU)
#define BCAP 34816       // per-bucket capacity (mean 32768 + 2048 ~ 11 sigma)
#define MP   32          // partial slices per edge pass
#define BPBQ 1024        // int4-quads per bucket_pass block -> 512 blocks
#define DEGU 41943040u   // 2^25 + 2^23: packed degree unit (sum field |.| << this)

typedef __attribute__((ext_vector_type(8))) short bf16x8;
typedef __attribute__((ext_vector_type(4))) float f32x4;

__device__ __forceinline__ float fast_tanh(float y) {
    float e = __expf(2.0f * y);
    return 1.0f - __fdividef(2.0f, 1.0f + e);
}

// f32 -> bf16 bits, round-to-nearest-even.
__device__ __forceinline__ unsigned f2b(float f) {
    union { float f; unsigned u; } v; v.f = f;
    return (v.u + 0x7FFFu + ((v.u >> 16) & 1u)) >> 16;
}

// ---- Bucket pass: counting-sort edges by dst>>11 into 64 buckets.
// Entry: (src << 11) | (dst & 2047)  -- 17+11 = 28 bits.
__global__ __launch_bounds__(256)
void bucket_pass(const int4* __restrict__ src4, const int4* __restrict__ dst4,
                 uint32_t* __restrict__ bkt, uint32_t* __restrict__ gcnt) {
    __shared__ uint32_t cnt[NRB], base[NRB], cur[NRB];
    if (threadIdx.x < NRB) { cnt[threadIdx.x] = 0u; cur[threadIdx.x] = 0u; }
    __syncthreads();
    const int q0 = blockIdx.x * BPBQ;
    for (int q = q0 + threadIdx.x; q < q0 + BPBQ; q += 256) {
        int4 d = dst4[q];
        atomicAdd(&cnt[(unsigned)d.x >> 11], 1u);
        atomicAdd(&cnt[(unsigned)d.y >> 11], 1u);
        atomicAdd(&cnt[(unsigned)d.z >> 11], 1u);
        atomicAdd(&cnt[(unsigned)d.w >> 11], 1u);
    }
    __syncthreads();
    if (threadIdx.x < NRB)
        base[threadIdx.x] = atomicAdd(&gcnt[threadIdx.x], cnt[threadIdx.x]);
    __syncthreads();
    for (int q = q0 + threadIdx.x; q < q0 + BPBQ; q += 256) {
        int4 d = dst4[q];
        int4 s = src4[q];
        unsigned b, idx;
        b = (unsigned)d.x >> 11; idx = base[b] + atomicAdd(&cur[b], 1u);
        if (idx >= BCAP) idx = BCAP - 1;   // defensive: never triggers, keeps writes in-bounds
        bkt[(size_t)b * BCAP + idx] = ((uint32_t)s.x << 11) | ((uint32_t)d.x & 2047u);
        b = (unsigned)d.y >> 11; idx = base[b] + atomicAdd(&cur[b], 1u);
        if (idx >= BCAP) idx = BCAP - 1;
        bkt[(size_t)b * BCAP + idx] = ((uint32_t)s.y << 11) | ((uint32_t)d.y & 2047u);
        b = (unsigned)d.z >> 11; idx = base[b] + atomicAdd(&cur[b], 1u);
        if (idx >= BCAP) idx = BCAP - 1;
        bkt[(size_t)b * BCAP + idx] = ((uint32_t)s.z << 11) | ((uint32_t)d.z & 2047u);
        b = (unsigned)d.w >> 11; idx = base[b] + atomicAdd(&cur[b], 1u);
        if (idx >= BCAP) idx = BCAP - 1;
        bkt[(size_t)b * BCAP + idx] = ((uint32_t)s.w << 11) | ((uint32_t)d.w & 2047u);
    }
}

// ---- Pass 1: block (m, r): LDS-accumulate packed (deg, sum_x) over its bucket chunk.
__global__ __launch_bounds__(256)
void edge_bin1(const float* __restrict__ x, const uint32_t* __restrict__ bkt,
               const uint32_t* __restrict__ gcnt, uint32_t* __restrict__ P1) {
    __shared__ uint32_t acc[RNGB];
    for (int i = threadIdx.x; i < RNGB; i += 256) acc[i] = 0u;
    __syncthreads();
    const int r = blockIdx.y;
    int cnt = (int)gcnt[r];
    if (cnt > BCAP) cnt = BCAP;            // defensive
    const int per = (cnt + MP - 1) / MP;
    int i0 = blockIdx.x * per;
    int i1 = i0 + per; if (i1 > cnt) i1 = cnt;
    const uint32_t* bp = bkt + (size_t)r * BCAP;
    for (int i = i0 + threadIdx.x; i < i1; i += 256) {
        uint32_t pk = bp[i];
        uint32_t s = pk >> 11, l = pk & 2047u;
        atomicAdd(&acc[l], DEGU + (uint32_t)(int)rintf(x[s] * 65536.0f));
    }
    __syncthreads();
    uint32_t* o = P1 + (size_t)blockIdx.x * NT + r * RNGB;
    for (int i = threadIdx.x; i < RNGB; i += 256) o[i] = acc[i];
}

// ---- Per-node: sum MP packed partials, unpack (deg, sum), compute a, c, 1/deg.
__global__ __launch_bounds__(256)
void node_pass(const float* __restrict__ x, const uint32_t* __restrict__ P1,
               const float* __restrict__ W1s, const float* __restrict__ W1n,
               const float* __restrict__ b1,
               const float* __restrict__ W2s, const float* __restrict__ W2n,
               float* __restrict__ aOut, float* __restrict__ cOut,
               float* __restrict__ dInv) {
    int v = blockIdx.x * blockDim.x + threadIdx.x;
    if (v >= NT) return;
    uint32_t T = 0u;
#pragma unroll 8
    for (int m = 0; m < MP; ++m) T += P1[(size_t)m * NT + v];
    float degf = rintf((float)T * (1.0f / (float)DEGU));
    uint32_t degu = (uint32_t)degf;
    int rem = (int)(T - degu * DEGU);
    float sm = (float)rem * (1.0f / 65536.0f);
    float dg = degf > 1.0f ? degf : 1.0f;
    float di = __fdividef(1.0f, dg);
    dInv[v] = di;
    float nb = sm * di;
    float xv = x[v];
    float a = 0.0f, c = 0.0f;
#pragma unroll 8
    for (int h = 0; h < HD; ++h) {
        float y = fmaf(xv, W1s[h], fmaf(nb, W1n[h], b1[h]));
        float t = fast_tanh(y);
        a = fmaf(t, W2s[h], a);
        c = fmaf(t, W2n[h], c);
    }
    aOut[v] = a;
    cOut[v] = c;
}

// ---- Pass 2: same structure, f32 LDS accumulate of c[src].
__global__ __launch_bounds__(256)
void edge_bin2(const float* __restrict__ c, const uint32_t* __restrict__ bkt,
               const uint32_t* __restrict__ gcnt, float* __restrict__ P2) {
    __shared__ float acc[RNGB];
    for (int i = threadIdx.x; i < RNGB; i += 256) acc[i] = 0.0f;
    __syncthreads();
    const int r = blockIdx.y;
    int cnt = (int)gcnt[r];
    if (cnt > BCAP) cnt = BCAP;            // defensive
    const int per = (cnt + MP - 1) / MP;
    int i0 = blockIdx.x * per;
    int i1 = i0 + per; if (i1 > cnt) i1 = cnt;
    const uint32_t* bp = bkt + (size_t)r * BCAP;
    for (int i = i0 + threadIdx.x; i < i1; i += 256) {
        uint32_t pk = bp[i];
        uint32_t s = pk >> 11, l = pk & 2047u;
        atomicAdd(&acc[l], c[s]);
    }
    __syncthreads();
    float* o = P2 + (size_t)blockIdx.x * NT + r * RNGB;
    for (int i = threadIdx.x; i < RNGB; i += 256) o[i] = acc[i];
}

// ---- out1[v] = a + (sum_m P2)*dInv + b2; h2 (bf16) = tanh(concat(out1, x)).
__global__ __launch_bounds__(256)
void finalize_k(const float* __restrict__ aA, const float* __restrict__ P2,
                const float* __restrict__ dInv, const float* __restrict__ x,
                const float* __restrict__ b2, float* __restrict__ out1,
                unsigned short* __restrict__ h2b) {
    int v = blockIdx.x * blockDim.x + threadIdx.x;
    if (v >= NT) return;
    float s2 = 0.0f;
#pragma unroll 8
    for (int m = 0; m < MP; ++m) s2 += P2[(size_t)m * NT + v];
    float o1 = fmaf(s2, dInv[v], aA[v] + b2[0]);
    out1[v] = o1;
    int b = v >> 11;          // v / 2048
    int j = v & (NPG - 1);    // v % 2048
    h2b[b * JTOT + j] = (unsigned short)f2b(fast_tanh(o1));
    h2b[b * JTOT + NPG + j] = (unsigned short)f2b(fast_tanh(x[v]));
}

// ---- MFMA split-K GEMM: part[kc] = h2b[64, k-chunk] x W3[k-chunk, 128-col tile].
// A-frag: lane&15 = m-row, lane>>4 = k-octet; B-frag: lane&15 = n-col, lane>>4 = k-octet
// C/D: col = lane&15, row = 4*(lane>>4) + reg   [layouts HW-verified, round 9 passed]
__global__ __launch_bounds__(256)
void gemm_mfma(const unsigned short* __restrict__ h2b, const float* __restrict__ W3,
               float* __restrict__ part) {
    __shared__ int4 Al[64 * 17];    // A: 64 rows x 16 chunks(16B=8 bf16), stride 17 (pad)
    __shared__ int4 Bl[16 * 130];   // B^T: 16 k-octets x 128 cols, stride 130 (pad)
    const int t = threadIdx.x;
    const int n0 = blockIdx.x * 128;
    const int k0 = blockIdx.y * KC;

    // stage A: rows 0..63 (= batch), k-window [k0, k0+128)
    {
        const int row = t >> 2;
        const int cb = t & 3;
        const int4* g = (const int4*)(h2b + (size_t)row * JTOT + k0);
#pragma unroll
        for (int i = 0; i < 4; ++i) {
            int cidx = cb + 4 * i;
            Al[row * 17 + cidx] = g[cidx];
        }
    }
    // stage B: W3[k0..+128][n0..+128) f32 -> bf16; Bl[kg][n] holds k = kg*8..+8 of col n
    for (int p = 0; p < 8; ++p) {
        int idx = p * 256 + t;
        int kg = idx >> 7;            // 0..15
        int n  = idx & 127;
        const float* g = W3 + (size_t)(k0 + kg * 8) * NPG + n0 + n;
        unsigned p0 = f2b(g[0 * NPG]) | (f2b(g[1 * NPG]) << 16);
        unsigned p1 = f2b(g[2 * NPG]) | (f2b(g[3 * NPG]) << 16);
        unsigned p2 = f2b(g[4 * NPG]) | (f2b(g[5 * NPG]) << 16);
        unsigned p3 = f2b(g[6 * NPG]) | (f2b(g[7 * NPG]) << 16);
        int4 v; v.x = (int)p0; v.y = (int)p1; v.z = (int)p2; v.w = (int)p3;
        Bl[kg * 130 + n] = v;
    }
    __syncthreads();

    const int lane = t & 63;
    const int w = t >> 6;             // wave 0..3 -> rows [16w, 16w+16)
    const int lr = lane & 15;
    const int lg = lane >> 4;

    f32x4 acc[8];
#pragma unroll
    for (int ct = 0; ct < 8; ++ct) acc[ct] = (f32x4){0.f, 0.f, 0.f, 0.f};

#pragma unroll
    for (int ksb = 0; ksb < 4; ++ksb) {
        bf16x8 a = *(const bf16x8*)&Al[(16 * w + lr) * 17 + ksb * 4 + lg];
#pragma unroll
        for (int ct = 0; ct < 8; ++ct) {
            bf16x8 b = *(const bf16x8*)&Bl[(ksb * 4 + lg) * 130 + 16 * ct + lr];
            acc[ct] = __builtin_amdgcn_mfma_f32_16x16x32_bf16(a, b, acc[ct], 0, 0, 0);
        }
    }

    float* p = part + ((size_t)blockIdx.y * BB) * NPG + n0;
#pragma unroll
    for (int ct = 0; ct < 8; ++ct) {
        int n = 16 * ct + lr;
#pragma unroll
        for (int r = 0; r < 4; ++r) {
            int m = 16 * w + 4 * lg + r;
            p[(size_t)m * NPG + n] = acc[ct][r];
        }
    }
}

__global__ __launch_bounds__(256)
void reduce_out2(const float* __restrict__ part, const float* __restrict__ b3,
                 float* __restrict__ out2) {
    int i = blockIdx.x * blockDim.x + threadIdx.x;
    if (i >= BB * NPG) return;
    int n = i & (NPG - 1);
    float s = b3[n];
#pragma unroll
    for (int k = 0; k < KS; ++k) s += part[(size_t)k * (BB * NPG) + i];
    out2[i] = s;
}

extern "C" void kernel_launch(void* const* d_in, const int* in_sizes, int n_in,
                              void* d_out, int out_size, void* d_ws, size_t ws_size,
                              hipStream_t stream) {
    const float* x   = (const float*)d_in[0];
    const int*   src = (const int*)d_in[1];
    const int*   dst = (const int*)d_in[2];
    const float* W1s = (const float*)d_in[3];
    const float* W1n = (const float*)d_in[4];
    const float* b1  = (const float*)d_in[5];
    const float* W2s = (const float*)d_in[6];
    const float* W2n = (const float*)d_in[7];
    const float* b2  = (const float*)d_in[8];
    const float* W3  = (const float*)d_in[9];
    const float* b3  = (const float*)d_in[10];

    float* out1 = (float*)d_out;            // NT
    float* out2 = (float*)d_out + NT;       // BB*NPG

    // Workspace layout:
    //   head: aA, cC, dInv (NT f32 each), h2b (BB*JTOT bf16)
    //   gcnt (64 u32), bkt (NRB*BCAP u32 = 8.5 MB)
    //   shared 16 MB region reused sequentially: P1 -> P2 -> part
    float* aA   = (float*)d_ws;
    float* cC   = aA + NT;
    float* dInv = cC + NT;
    unsigned short* h2b = (unsigned short*)(dInv + NT);
    uint32_t* gcnt = (uint32_t*)(h2b + (size_t)BB * JTOT);
    uint32_t* bkt  = gcnt + 64;
    char* shared16 = (char*)(bkt + (size_t)NRB * BCAP);

    uint32_t* P1   = (uint32_t*)shared16;   // [MP][NT]
    float*    P2   = (float*)shared16;      // [MP][NT]      (after P1 dead)
    float*    part = (float*)shared16;      // [KS][BB][NPG] (after P2 dead)

    hipMemsetAsync(gcnt, 0, NRB * sizeof(uint32_t), stream);

    bucket_pass<<<QT / BPBQ, 256, 0, stream>>>((const int4*)src, (const int4*)dst, bkt, gcnt);
    edge_bin1<<<dim3(MP, NRB), 256, 0, stream>>>(x, bkt, gcnt, P1);
    node_pass<<<NT / 256, 256, 0, stream>>>(x, P1, W1s, W1n, b1, W2s, W2n, aA, cC, dInv);
    edge_bin2<<<dim3(MP, NRB), 256, 0, stream>>>(cC, bkt, gcnt, P2);
    finalize_k<<<NT / 256, 256, 0, stream>>>(aA, P2, dInv, x, b2, out1, h2b);
    gemm_mfma<<<dim3(NPG / 128, KS), 256, 0, stream>>>(h2b, W3, part);
    reduce_out2<<<(BB * NPG + 255) / 256, 256, 0, stream>>>(part, b3, out2);
}

// Round 13
// 187.755 us; speedup vs baseline: 3.0266x; 1.0089x over previous
//
#include <hip/hip_runtime.h>
#include <stdint.h>

// Problem constants (fixed by the reference).
#define NT   131072      // total nodes
#define ET   2097152     // edges
#define QT   (ET / 4)    // int4 quads
#define HD   128         // hidden dim
#define BB   64          // batch (graphs)
#define NPG  2048        // nodes per graph
#define JTOT 4096        // 2*NPG (concat width)
#define KS   16          // split-K chunks for final GEMM
#define KC   (JTOT / KS) // 256 (2 x 128 staged sub-steps)

#define NRB  64          // destination-range buckets
#define RNGB 2048        // nodes per bucket (8 KB LDS accumulator)
#define BCAP 34816       // per-bucket capacity (mean 32768 + ~11 sigma)
#define MP   16          // partial slices per edge pass (1024 blocks, 4/CU)
#define BPBQ 1024        // int4-quads per bucket_pass block -> 512 blocks
#define DEGU 41943040u   // 2^25 + 2^23: packed degree unit (sum field |.| << this)

typedef __attribute__((ext_vector_type(8))) short bf16x8;
typedef __attribute__((ext_vector_type(4))) float f32x4;

__device__ __forceinline__ float fast_tanh(float y) {
    float e = __expf(2.0f * y);
    return 1.0f - __fdividef(2.0f, 1.0f + e);
}

// f32 -> bf16 bits, round-to-nearest-even.
__device__ __forceinline__ unsigned f2b(float f) {
    union { float f; unsigned u; } v; v.f = f;
    return (v.u + 0x7FFFu + ((v.u >> 16) & 1u)) >> 16;
}

// ---- Bucket pass: counting-sort edges by dst>>11 into 64 buckets.
// Entry: (src << 11) | (dst & 2047)  -- 17+11 = 28 bits.
__global__ __launch_bounds__(256)
void bucket_pass(const int4* __restrict__ src4, const int4* __restrict__ dst4,
                 uint32_t* __restrict__ bkt, uint32_t* __restrict__ gcnt) {
    __shared__ uint32_t cnt[NRB], base[NRB], cur[NRB];
    if (threadIdx.x < NRB) { cnt[threadIdx.x] = 0u; cur[threadIdx.x] = 0u; }
    __syncthreads();
    const int q0 = blockIdx.x * BPBQ;
    for (int q = q0 + threadIdx.x; q < q0 + BPBQ; q += 256) {
        int4 d = dst4[q];
        atomicAdd(&cnt[(unsigned)d.x >> 11], 1u);
        atomicAdd(&cnt[(unsigned)d.y >> 11], 1u);
        atomicAdd(&cnt[(unsigned)d.z >> 11], 1u);
        atomicAdd(&cnt[(unsigned)d.w >> 11], 1u);
    }
    __syncthreads();
    if (threadIdx.x < NRB)
        base[threadIdx.x] = atomicAdd(&gcnt[threadIdx.x], cnt[threadIdx.x]);
    __syncthreads();
    for (int q = q0 + threadIdx.x; q < q0 + BPBQ; q += 256) {
        int4 d = dst4[q];
        int4 s = src4[q];
        unsigned b, idx;
        b = (unsigned)d.x >> 11; idx = base[b] + atomicAdd(&cur[b], 1u);
        if (idx >= BCAP) idx = BCAP - 1;   // defensive: never triggers, keeps writes in-bounds
        bkt[(size_t)b * BCAP + idx] = ((uint32_t)s.x << 11) | ((uint32_t)d.x & 2047u);
        b = (unsigned)d.y >> 11; idx = base[b] + atomicAdd(&cur[b], 1u);
        if (idx >= BCAP) idx = BCAP - 1;
        bkt[(size_t)b * BCAP + idx] = ((uint32_t)s.y << 11) | ((uint32_t)d.y & 2047u);
        b = (unsigned)d.z >> 11; idx = base[b] + atomicAdd(&cur[b], 1u);
        if (idx >= BCAP) idx = BCAP - 1;
        bkt[(size_t)b * BCAP + idx] = ((uint32_t)s.z << 11) | ((uint32_t)d.z & 2047u);
        b = (unsigned)d.w >> 11; idx = base[b] + atomicAdd(&cur[b], 1u);
        if (idx >= BCAP) idx = BCAP - 1;
        bkt[(size_t)b * BCAP + idx] = ((uint32_t)s.w << 11) | ((uint32_t)d.w & 2047u);
    }
}

// ---- Pass 1: block (m, r): LDS-accumulate packed (deg, sum_x) over its bucket chunk.
// uint4 reads: 4 edges/thread/iter -> 4x outstanding x[] gathers.
__global__ __launch_bounds__(256)
void edge_bin1(const float* __restrict__ x, const uint32_t* __restrict__ bkt,
               const uint32_t* __restrict__ gcnt, uint32_t* __restrict__ P1) {
    __shared__ uint32_t acc[RNGB];
    for (int i = threadIdx.x; i < RNGB; i += 256) acc[i] = 0u;
    __syncthreads();
    const int r = blockIdx.y;
    int cnt = (int)gcnt[r];
    if (cnt > BCAP) cnt = BCAP;            // defensive
    int per = ((cnt + MP - 1) / MP + 7) & ~7;   // multiple of 8 -> i0 aligned for uint4
    int i0 = blockIdx.x * per;
    int i1 = i0 + per; if (i1 > cnt) i1 = cnt;
    const uint32_t* bp = bkt + (size_t)r * BCAP;
    for (int i = i0 + (int)threadIdx.x * 4; i < i1; i += 1024) {
        if (i + 4 <= i1) {
            uint4 pk4 = *reinterpret_cast<const uint4*>(bp + i);
            float x0 = x[pk4.x >> 11], x1 = x[pk4.y >> 11];
            float x2 = x[pk4.z >> 11], x3 = x[pk4.w >> 11];
            atomicAdd(&acc[pk4.x & 2047u], DEGU + (uint32_t)(int)rintf(x0 * 65536.0f));
            atomicAdd(&acc[pk4.y & 2047u], DEGU + (uint32_t)(int)rintf(x1 * 65536.0f));
            atomicAdd(&acc[pk4.z & 2047u], DEGU + (uint32_t)(int)rintf(x2 * 65536.0f));
            atomicAdd(&acc[pk4.w & 2047u], DEGU + (uint32_t)(int)rintf(x3 * 65536.0f));
        } else {
            for (int j = i; j < i1; ++j) {
                uint32_t pk = bp[j];
                atomicAdd(&acc[pk & 2047u], DEGU + (uint32_t)(int)rintf(x[pk >> 11] * 65536.0f));
            }
        }
    }
    __syncthreads();
    uint32_t* o = P1 + (size_t)blockIdx.x * NT + r * RNGB;
    for (int i = threadIdx.x; i < RNGB; i += 256) o[i] = acc[i];
}

// ---- Per-node: sum MP packed partials, unpack (deg, sum), compute a, c, 1/deg.
__global__ __launch_bounds__(256)
void node_pass(const float* __restrict__ x, const uint32_t* __restrict__ P1,
               const float* __restrict__ W1s, const float* __restrict__ W1n,
               const float* __restrict__ b1,
               const float* __restrict__ W2s, const float* __restrict__ W2n,
               float* __restrict__ aOut, float* __restrict__ cOut,
               float* __restrict__ dInv) {
    int v = blockIdx.x * blockDim.x + threadIdx.x;
    if (v >= NT) return;
    uint32_t T = 0u;
#pragma unroll 8
    for (int m = 0; m < MP; ++m) T += P1[(size_t)m * NT + v];
    float degf = rintf((float)T * (1.0f / (float)DEGU));
    uint32_t degu = (uint32_t)degf;
    int rem = (int)(T - degu * DEGU);
    float sm = (float)rem * (1.0f / 65536.0f);
    float dg = degf > 1.0f ? degf : 1.0f;
    float di = __fdividef(1.0f, dg);
    dInv[v] = di;
    float nb = sm * di;
    float xv = x[v];
    float a = 0.0f, c = 0.0f;
#pragma unroll 8
    for (int h = 0; h < HD; ++h) {
        float y = fmaf(xv, W1s[h], fmaf(nb, W1n[h], b1[h]));
        float t = fast_tanh(y);
        a = fmaf(t, W2s[h], a);
        c = fmaf(t, W2n[h], c);
    }
    aOut[v] = a;
    cOut[v] = c;
}

// ---- Pass 2: same structure, f32 LDS accumulate of c[src].
__global__ __launch_bounds__(256)
void edge_bin2(const float* __restrict__ c, const uint32_t* __restrict__ bkt,
               const uint32_t* __restrict__ gcnt, float* __restrict__ P2) {
    __shared__ float acc[RNGB];
    for (int i = threadIdx.x; i < RNGB; i += 256) acc[i] = 0.0f;
    __syncthreads();
    const int r = blockIdx.y;
    int cnt = (int)gcnt[r];
    if (cnt > BCAP) cnt = BCAP;            // defensive
    int per = ((cnt + MP - 1) / MP + 7) & ~7;
    int i0 = blockIdx.x * per;
    int i1 = i0 + per; if (i1 > cnt) i1 = cnt;
    const uint32_t* bp = bkt + (size_t)r * BCAP;
    for (int i = i0 + (int)threadIdx.x * 4; i < i1; i += 1024) {
        if (i + 4 <= i1) {
            uint4 pk4 = *reinterpret_cast<const uint4*>(bp + i);
            float c0 = c[pk4.x >> 11], c1 = c[pk4.y >> 11];
            float c2 = c[pk4.z >> 11], c3 = c[pk4.w >> 11];
            atomicAdd(&acc[pk4.x & 2047u], c0);
            atomicAdd(&acc[pk4.y & 2047u], c1);
            atomicAdd(&acc[pk4.z & 2047u], c2);
            atomicAdd(&acc[pk4.w & 2047u], c3);
        } else {
            for (int j = i; j < i1; ++j) {
                uint32_t pk = bp[j];
                atomicAdd(&acc[pk & 2047u], c[pk >> 11]);
            }
        }
    }
    __syncthreads();
    float* o = P2 + (size_t)blockIdx.x * NT + r * RNGB;
    for (int i = threadIdx.x; i < RNGB; i += 256) o[i] = acc[i];
}

// ---- out1[v] = a + (sum_m P2)*dInv + b2; h2 (bf16) = tanh(concat(out1, x)).
__global__ __launch_bounds__(256)
void finalize_k(const float* __restrict__ aA, const float* __restrict__ P2,
                const float* __restrict__ dInv, const float* __restrict__ x,
                const float* __restrict__ b2, float* __restrict__ out1,
                unsigned short* __restrict__ h2b) {
    int v = blockIdx.x * blockDim.x + threadIdx.x;
    if (v >= NT) return;
    float s2 = 0.0f;
#pragma unroll 8
    for (int m = 0; m < MP; ++m) s2 += P2[(size_t)m * NT + v];
    float o1 = fmaf(s2, dInv[v], aA[v] + b2[0]);
    out1[v] = o1;
    int b = v >> 11;          // v / 2048
    int j = v & (NPG - 1);    // v % 2048
    h2b[b * JTOT + j] = (unsigned short)f2b(fast_tanh(o1));
    h2b[b * JTOT + NPG + j] = (unsigned short)f2b(fast_tanh(x[v]));
}

// ---- MFMA split-K GEMM: part[kc] = h2b[64, KC] x W3[KC, 128-col tile].
// KC=256 processed as 2 staged sub-steps of 128; accumulators persist.
// A-frag: lane&15 = m-row, lane>>4 = k-octet; B-frag: lane&15 = n-col, lane>>4 = k-octet
// C/D: col = lane&15, row = 4*(lane>>4) + reg   [layouts HW-verified, round 9 passed]
__global__ __launch_bounds__(256)
void gemm_mfma(const unsigned short* __restrict__ h2b, const float* __restrict__ W3,
               float* __restrict__ part) {
    __shared__ int4 Al[64 * 17];    // A: 64 rows x 16 chunks(16B=8 bf16), stride 17 (pad)
    __shared__ int4 Bl[16 * 130];   // B^T: 16 k-octets x 128 cols, stride 130 (pad)
    const int t = threadIdx.x;
    const int n0 = blockIdx.x * 128;

    const int lane = t & 63;
    const int w = t >> 6;             // wave 0..3 -> rows [16w, 16w+16)
    const int lr = lane & 15;
    const int lg = lane >> 4;

    f32x4 acc[8];
#pragma unroll
    for (int ct = 0; ct < 8; ++ct) acc[ct] = (f32x4){0.f, 0.f, 0.f, 0.f};

    for (int kc2 = 0; kc2 < 2; ++kc2) {
        const int k0 = blockIdx.y * KC + kc2 * 128;

        // stage A: rows 0..63 (= batch), k-window [k0, k0+128)
        {
            const int row = t >> 2;
            const int cb = t & 3;
            const int4* g = (const int4*)(h2b + (size_t)row * JTOT + k0);
#pragma unroll
            for (int i = 0; i < 4; ++i) {
                int cidx = cb + 4 * i;
                Al[row * 17 + cidx] = g[cidx];
            }
        }
        // stage B: W3[k0..+128][n0..+128) f32 -> bf16; Bl[kg][n] = k-octet kg of col n
        for (int p = 0; p < 8; ++p) {
            int idx = p * 256 + t;
            int kg = idx >> 7;            // 0..15
            int n  = idx & 127;
            const float* g = W3 + (size_t)(k0 + kg * 8) * NPG + n0 + n;
            unsigned p0 = f2b(g[0 * NPG]) | (f2b(g[1 * NPG]) << 16);
            unsigned p1 = f2b(g[2 * NPG]) | (f2b(g[3 * NPG]) << 16);
            unsigned p2 = f2b(g[4 * NPG]) | (f2b(g[5 * NPG]) << 16);
            unsigned p3 = f2b(g[6 * NPG]) | (f2b(g[7 * NPG]) << 16);
            int4 v; v.x = (int)p0; v.y = (int)p1; v.z = (int)p2; v.w = (int)p3;
            Bl[kg * 130 + n] = v;
        }
        __syncthreads();

#pragma unroll
        for (int ksb = 0; ksb < 4; ++ksb) {
            bf16x8 a = *(const bf16x8*)&Al[(16 * w + lr) * 17 + ksb * 4 + lg];
#pragma unroll
            for (int ct = 0; ct < 8; ++ct) {
                bf16x8 b = *(const bf16x8*)&Bl[(ksb * 4 + lg) * 130 + 16 * ct + lr];
                acc[ct] = __builtin_amdgcn_mfma_f32_16x16x32_bf16(a, b, acc[ct], 0, 0, 0);
            }
        }
        __syncthreads();   // all waves done reading before next-stage overwrite
    }

    float* p = part + ((size_t)blockIdx.y * BB) * NPG + n0;
#pragma unroll
    for (int ct = 0; ct < 8; ++ct) {
        int n = 16 * ct + lr;
#pragma unroll
        for (int r = 0; r < 4; ++r) {
            int m = 16 * w + 4 * lg + r;
            p[(size_t)m * NPG + n] = acc[ct][r];
        }
    }
}

__global__ __launch_bounds__(256)
void reduce_out2(const float* __restrict__ part, const float* __restrict__ b3,
                 float* __restrict__ out2) {
    int i = blockIdx.x * blockDim.x + threadIdx.x;
    if (i >= BB * NPG) return;
    int n = i & (NPG - 1);
    float s = b3[n];
#pragma unroll
    for (int k = 0; k < KS; ++k) s += part[(size_t)k * (BB * NPG) + i];
    out2[i] = s;
}

extern "C" void kernel_launch(void* const* d_in, const int* in_sizes, int n_in,
                              void* d_out, int out_size, void* d_ws, size_t ws_size,
                              hipStream_t stream) {
    const float* x   = (const float*)d_in[0];
    const int*   src = (const int*)d_in[1];
    const int*   dst = (const int*)d_in[2];
    const float* W1s = (const float*)d_in[3];
    const float* W1n = (const float*)d_in[4];
    const float* b1  = (const float*)d_in[5];
    const float* W2s = (const float*)d_in[6];
    const float* W2n = (const float*)d_in[7];
    const float* b2  = (const float*)d_in[8];
    const float* W3  = (const float*)d_in[9];
    const float* b3  = (const float*)d_in[10];

    float* out1 = (float*)d_out;            // NT
    float* out2 = (float*)d_out + NT;       // BB*NPG

    // Workspace layout:
    //   head: aA, cC, dInv (NT f32 each), h2b (BB*JTOT bf16)
    //   gcnt (64 u32), bkt (NRB*BCAP u32 = 8.5 MB)
    //   shared region reused sequentially: P1 -> P2 -> part (max 8 MB)
    float* aA   = (float*)d_ws;
    float* cC   = aA + NT;
    float* dInv = cC + NT;
    unsigned short* h2b = (unsigned short*)(dInv + NT);
    uint32_t* gcnt = (uint32_t*)(h2b + (size_t)BB * JTOT);
    uint32_t* bkt  = gcnt + 64;
    char* shared8 = (char*)(bkt + (size_t)NRB * BCAP);

    uint32_t* P1   = (uint32_t*)shared8;   // [MP][NT]       = 8 MB
    float*    P2   = (float*)shared8;      // [MP][NT]       (after P1 dead)
    float*    part = (float*)shared8;      // [KS][BB][NPG]  = 8 MB (after P2 dead)

    hipMemsetAsync(gcnt, 0, NRB * sizeof(uint32_t), stream);

    bucket_pass<<<QT / BPBQ, 256, 0, stream>>>((const int4*)src, (const int4*)dst, bkt, gcnt);
    edge_bin1<<<dim3(MP, NRB), 256, 0, stream>>>(x, bkt, gcnt, P1);
    node_pass<<<NT / 256, 256, 0, stream>>>(x, P1, W1s, W1n, b1, W2s, W2n, aA, cC, dInv);
    edge_bin2<<<dim3(MP, NRB), 256, 0, stream>>>(cC, bkt, gcnt, P2);
    finalize_k<<<NT / 256, 256, 0, stream>>>(aA, P2, dInv, x, b2, out1, h2b);
    gemm_mfma<<<dim3(NPG / 128, KS), 256, 0, stream>>>(h2b, W3, part);
    reduce_out2<<<(BB * NPG + 255) / 256, 256, 0, stream>>>(part, b3, out2);
}